// Round 14
// baseline (82.101 us; speedup 1.0000x reference)
//
#include <hip/hip_runtime.h>
#include <math.h>

#define IH 512
#define IW 512
#define NPX (IH*IW)

// column-D + dpp-shift-box geometry
#define TW 60                // output columns per tile (64 lanes -> D cols -2..61)
#define BH 16                // tile height (4 waves x 4 rows)
#define NXT 9                // ceil(512/60)
#define YROWS 30             // image rows -7..22
#define YCOLS 74             // image cols -7..66
#define YSZ2 (YROWS*YCOLS)   // 2220 floats = 8880 B (only LDS)

// mono-fallback geometry (round-5 kernel)
#define TS 32
#define YHALO 7
#define RHALO 5
#define YD (TS + 2*YHALO)
#define RD (TS + 2*RHALO)
#define RSZ (RD*RD)
#define MYSZ (YD*YD)

#define FSQRT(x) __builtin_amdgcn_sqrtf(x)
#if __has_builtin(__builtin_amdgcn_exp2f)
#define FEXP2(x) __builtin_amdgcn_exp2f(x)
#else
#define FEXP2(x) exp2f(x)
#endif

// DPP wave_shl:1 (ctrl 0x130): lane i <- lane i+1, whole-wave, lane63 <- 0.
__device__ __forceinline__ float dpp_shl1(float x) {
    return __int_as_float(__builtin_amdgcn_update_dpp(
        0, __float_as_int(x), 0x130, 0xf, 0xf, true));
}

// ---------------- column-D compute kernel: dx-group per blockIdx.z -----------
// Round-13 post-mortem: VALU-busy time == issue floor (~13us); the 60% idle is
// too-few resident waves. All rounds since r9 sat in the 65-128 VGPR band
// (4 waves/SIMD cap) with 6.75 blocks/CU needing 2 generations. This version
// forces VGPR<=64 (8 waves/SIMD -> all blocks co-resident, ONE generation):
// (a) rb[14] -> 1 rolling RGB offset reg ((o+512)&(NPX-1) per k),
// (b) RGB register-window prefetch depth 1 (3 regs),
// (c) __launch_bounds__(256,8). Diet makes the clamp safe (persistent live
//     set ~50 regs) -- unlike round-2's 104->64 spill disaster.
// Spill tell: FETCH/WRITE_SIZE explosion. Watch it.
__global__ __launch_bounds__(256, 8)
void nlm_part(const float* __restrict__ rgb,
              const float* __restrict__ sigma,
              float4* __restrict__ ws) {
    __shared__ float YL[YSZ2];

    const int tid   = threadIdx.x;
    const int lane  = tid & 63;
    const int wavei = tid >> 6;
    const int tx0 = blockIdx.x * TW;
    const int ty0 = blockIdx.y * BH;
    const int slice = blockIdx.z;
    const int nz = gridDim.z;

    const float* Rp = rgb;
    const float* Gp = rgb + NPX;
    const float* Bp = rgb + 2*NPX;

    // stage luminance: rows -7..22, cols -7..66 (circular)
    for (int idx = tid; idx < YSZ2; idx += 256) {
        int a = idx / YCOLS, b = idx - a*YCOLS;
        int gy = (ty0 + a - 7) & (IH-1);
        int gx = (tx0 + b - 7) & (IW-1);
        int g = gy*IW + gx;
        YL[idx] = 0.299f*Rp[g] + 0.587f*Gp[g] + 0.114f*Bp[g];
    }
    __syncthreads();

    const float m2 = -1.4426950408889634f /
                     (fmaxf(sigma[0]*2.0f, 0.0f) + 1e-6f);

    const int l  = lane;         // D col cd = l-2; output col = l (<60)
    const int r0 = wavei*4;      // strip start row

    // minuend Y at D col cd=l-2: rows r0-2..r0+5  (LDS: row r0+5+i, col l+5)
    float yb8[8];
    #pragma unroll
    for (int i = 0; i < 8; ++i)
        yb8[i] = YL[(r0+5+i)*YCOLS + (l+5)];

    float accR[4]={0,0,0,0}, accG[4]={0,0,0,0},
          accB[4]={0,0,0,0}, den[4]={0,0,0,0};

    int dxlo, dxcnt;
    if (nz == 6) { if (slice < 5) { dxlo = -5 + 2*slice; dxcnt = 2; }
                   else           { dxlo = 5;            dxcnt = 1; } }
    else         { if (slice < 3) { dxlo = -5 + 3*slice; dxcnt = 3; }
                   else           { dxlo = 4;            dxcnt = 2; } }

    for (int u = 0; u < dxcnt; ++u) {
        const int dx = dxlo + u;
        const int ysb  = r0*YCOLS + (l + 5 - dx);     // Y subtrahend col base
        const int coli = (tx0 + l - dx) & (IW-1);     // rgb column (circular)

        // rolling Y subtrahend rows: slot j holds storage row j at k=0
        float sub8[8];
        #pragma unroll
        for (int j = 0; j < 8; ++j)
            sub8[j] = YL[ysb + j*YCOLS];
        float nY = YL[ysb + 8*YCOLS];                 // 1-deep Y prefetch

        // RGB window rows 0..3 (image rows ty0+r0-5..-2) + 1-deep prefetch
        float rw[4], gw[4], bw[4];
        #pragma unroll
        for (int s = 0; s < 4; ++s) {
            int o = (((ty0 + r0 - 5 + s) & (IH-1)) << 9) + coli;
            rw[s] = Rp[o]; gw[s] = Gp[o]; bw[s] = Bp[o];
        }
        // rolling offset register (replaces rb[14]): points at row q=4
        int oP = (((ty0 + r0 - 1) & (IH-1)) << 9) + coli;
        float rA = Rp[oP], gA = Gp[oP], bA = Bp[oP];  // row 4, consume at k=1
        oP = (oP + IW) & (NPX-1);                     // -> row 5

        #pragma unroll
        for (int k = 0; k <= 10; ++k) {               // dy = 5 - k
            if (k > 0) {
                sub8[(k+7)&7] = nY;                   // Y row k+7
                if (k < 10) nY = YL[ysb + (8+k)*YCOLS];
                rw[(k+3)&3] = rA; gw[(k+3)&3] = gA; bw[(k+3)&3] = bA;
                if (k <= 9) {                         // load row k+4
                    rA = Rp[oP]; gA = Gp[oP]; bA = Bp[oP];
                    oP = (oP + IW) & (NPX-1);
                }
            }
            // own-column E + vertical box via prefix (square folded into fma)
            float pre[9]; pre[0] = 0.f;
            #pragma unroll
            for (int i = 0; i < 8; ++i) {
                float d = yb8[i] - sub8[(i+k)&7];
                pre[i+1] = fmaf(d, d, pre[i]);
            }
            float V[4];
            #pragma unroll
            for (int rr = 0; rr < 4; ++rr) V[rr] = pre[rr+5] - pre[rr];

            // horizontal 5-col box over lanes l..l+4 via chained dpp shifts
            float box[4];
            #pragma unroll
            for (int rr = 0; rr < 4; ++rr) {
                float s1 = dpp_shl1(V[rr]);           // V[l+1]
                float s2 = dpp_shl1(s1);              // V[l+2]
                float s3 = dpp_shl1(s2);              // V[l+3]
                float s4 = dpp_shl1(s3);              // V[l+4]
                box[rr] = ((V[rr] + s1) + (s2 + s3)) + s4;
            }
            #pragma unroll
            for (int rr = 0; rr < 4; ++rr) {
                float w = FEXP2(FSQRT(fmaxf(box[rr], 0.f)) * m2);
                accR[rr] = fmaf(w, rw[(k+rr)&3], accR[rr]);
                accG[rr] = fmaf(w, gw[(k+rr)&3], accG[rr]);
                accB[rr] = fmaf(w, bw[(k+rr)&3], accB[rr]);
                den[rr] += w;
            }
        }
    }

    if (l < TW && tx0 + l < IW) {
        #pragma unroll
        for (int rr = 0; rr < 4; ++rr) {
            int px = (ty0 + r0 + rr)*IW + tx0 + l;
            ws[(size_t)slice*NPX + px] =
                make_float4(accR[rr], accG[rr], accB[rr], den[rr]);
        }
    }
}

// ---------------- combine: sum nslice slices, normalize, clip ----------------
__global__ __launch_bounds__(256)
void nlm_combine(const float4* __restrict__ ws, float* __restrict__ out,
                 int nslice) {
    int px = blockIdx.x * 256 + threadIdx.x;
    float r = 0.f, g = 0.f, b = 0.f, w = 0.f;
    for (int s = 0; s < nslice; ++s) {
        float4 v = ws[(size_t)s * NPX + px];
        r += v.x; g += v.y; b += v.z; w += v.w;
    }
    float iw = 1.0f / w;
    out[px]           = fminf(fmaxf(r * iw, 0.f), 1.f);
    out[NPX + px]     = fminf(fmaxf(g * iw, 0.f), 1.f);
    out[2 * NPX + px] = fminf(fmaxf(b * iw, 0.f), 1.f);
}

// ---------------- fallback: round-5 monolithic kernel (ws too small) ---------
__global__ __launch_bounds__(256)
void nlm_mono(const float* __restrict__ rgb,
              const float* __restrict__ sigma,
              float* __restrict__ out) {
    __shared__ float Y[MYSZ];
    __shared__ float RGBL[3 * RSZ];

    const int tid = threadIdx.x;
    const int tx0 = blockIdx.x * TS;
    const int ty0 = blockIdx.y * TS;

    const float* Rp = rgb;
    const float* Gp = rgb + NPX;
    const float* Bp = rgb + 2 * NPX;

    for (int idx = tid; idx < MYSZ; idx += 256) {
        int a = idx / YD, b = idx - a * YD;
        int gy = (ty0 + a - YHALO) & (IH - 1);
        int gx = (tx0 + b - YHALO) & (IW - 1);
        int g = gy * IW + gx;
        Y[idx] = 0.299f * Rp[g] + 0.587f * Gp[g] + 0.114f * Bp[g];
    }
    for (int idx = tid; idx < RSZ; idx += 256) {
        int a = idx / RD, b = idx - a * RD;
        int gy = (ty0 + a - RHALO) & (IH - 1);
        int gx = (tx0 + b - RHALO) & (IW - 1);
        int g = gy * IW + gx;
        RGBL[idx]           = Rp[g];
        RGBL[RSZ + idx]     = Gp[g];
        RGBL[2 * RSZ + idx] = Bp[g];
    }
    __syncthreads();

    const float minv_h = -1.0f / (fmaxf(sigma[0] * 2.0f, 0.0f) + 1e-6f);
    const int tx = tid & 31;
    const int tz = tid >> 5;
    const int r0 = tz * 4;

    const int ybase = (YHALO + r0 - 2) * YD + (YHALO + tx - 2);
    float yb[8][5];
    #pragma unroll
    for (int i = 0; i < 8; ++i)
        #pragma unroll
        for (int b = 0; b < 5; ++b)
            yb[i][b] = Y[ybase + i * YD + b];

    float accR[4] = {0.f,0.f,0.f,0.f}, accG[4] = {0.f,0.f,0.f,0.f};
    float accB[4] = {0.f,0.f,0.f,0.f}, den[4] = {0.f,0.f,0.f,0.f};

    for (int dx = -5; dx <= 5; ++dx) {
        const int ybd = (YHALO + r0 - 7) * YD + (YHALO + tx - 2 - dx);
        const int rbd = (RHALO + r0 - 5) * RD + (RHALO + tx - dx);

        #pragma unroll
        for (int k = 0; k <= 10; ++k) {
            float hs[8];
            #pragma unroll
            for (int i = 0; i < 8; ++i) {
                float s = 0.f;
                #pragma unroll
                for (int b = 0; b < 5; ++b) {
                    float d = yb[i][b] - Y[ybd + (i + k) * YD + b];
                    s = fmaf(d, d, s);
                }
                hs[i] = s;
            }
            float pre[9];
            pre[0] = 0.f;
            #pragma unroll
            for (int i = 0; i < 8; ++i) pre[i + 1] = pre[i] + hs[i];
            #pragma unroll
            for (int rr = 0; rr < 4; ++rr) {
                float box = pre[rr + 5] - pre[rr];
                float w = __expf(FSQRT(box) * minv_h);
                const int s2 = rbd + (rr + k) * RD;
                accR[rr] = fmaf(w, RGBL[s2], accR[rr]);
                accG[rr] = fmaf(w, RGBL[RSZ + s2], accG[rr]);
                accB[rr] = fmaf(w, RGBL[2 * RSZ + s2], accB[rr]);
                den[rr] += w;
            }
        }
    }

    #pragma unroll
    for (int rr = 0; rr < 4; ++rr) {
        int px = (ty0 + r0 + rr) * IW + tx0 + tx;
        float iw = 1.0f / den[rr];
        out[px]           = fminf(fmaxf(accR[rr] * iw, 0.f), 1.f);
        out[NPX + px]     = fminf(fmaxf(accG[rr] * iw, 0.f), 1.f);
        out[2 * NPX + px] = fminf(fmaxf(accB[rr] * iw, 0.f), 1.f);
    }
}

extern "C" void kernel_launch(void* const* d_in, const int* in_sizes, int n_in,
                              void* d_out, int out_size, void* d_ws, size_t ws_size,
                              hipStream_t stream) {
    const float* rgb   = (const float*)d_in[0];
    const float* sigma = (const float*)d_in[1];
    float* out = (float*)d_out;

    const size_t need6 = (size_t)6 * NPX * sizeof(float4);
    const size_t need4 = (size_t)4 * NPX * sizeof(float4);
    int nslice = (ws_size >= need6) ? 6 : (ws_size >= need4 ? 4 : 0);

    if (nslice > 0) {
        float4* ws = (float4*)d_ws;
        dim3 grid(NXT, IH / BH, nslice);   // 9 x 32 x {6|4}
        nlm_part<<<grid, dim3(256), 0, stream>>>(rgb, sigma, ws);
        nlm_combine<<<dim3(NPX / 256), dim3(256), 0, stream>>>(ws, out, nslice);
    } else {
        dim3 grid(IW / TS, IH / TS);
        nlm_mono<<<grid, dim3(256), 0, stream>>>(rgb, sigma, out);
    }
}

// Round 15
// 36.016 us; speedup vs baseline: 2.2796x; 2.2796x over previous
//
#include <hip/hip_runtime.h>
#include <math.h>

#define IH 512
#define IW 512
#define NPX (IH*IW)

// column-D + dpp-shift-box geometry, 2-row strips
#define TW 60                // output columns per tile (64 lanes -> D cols -2..61)
#define BH 8                 // tile height (4 waves x 2 rows)
#define NXT 9                // ceil(512/60)
#define YROWS 22             // image rows -7..14
#define YCOLS 74             // image cols -7..66
#define YSZ2 (YROWS*YCOLS)   // 1628 floats = 6512 B (only LDS)

// mono-fallback geometry (round-5 kernel)
#define TS 32
#define YHALO 7
#define RHALO 5
#define YD (TS + 2*YHALO)
#define RD (TS + 2*RHALO)
#define RSZ (RD*RD)
#define MYSZ (YD*YD)

#define FSQRT(x) __builtin_amdgcn_sqrtf(x)
#if __has_builtin(__builtin_amdgcn_exp2f)
#define FEXP2(x) __builtin_amdgcn_exp2f(x)
#else
#define FEXP2(x) exp2f(x)
#endif

// DPP wave_shl:1 (ctrl 0x130): lane i <- lane i+1, whole-wave, lane63 <- 0.
__device__ __forceinline__ float dpp_shl1(float x) {
    return __int_as_float(__builtin_amdgcn_update_dpp(
        0, __float_as_int(x), 0x130, 0xf, 0xf, true));
}

// ---------------- column-D compute kernel: dx-group per blockIdx.z -----------
// Round-14 post-mortem: occupancy lever is real (clamp -> 60% occ) but the
// 4-row working set (~75 regs) can't fit the 64-VGPR cliff -> 212MB spill.
// This version shrinks the WORK SET instead: 2 rows per thread (BH=8).
// Live set ~45-55 VGPR -> naturally <=64 (8 waves/SIMD) with NO clamp.
// LDS 6.4KB; grid 9x64x4 = 2304 blocks (~9/CU, ~one generation).
// Per shift: 1 Y ds_read + 3 RGB global (1-deep prefetch), 6 sub+6 fma prefix
// -> V[2], dpp 5-col box, 2x sqrt/exp2, 8 acc fma.
__global__ __launch_bounds__(256)
void nlm_part(const float* __restrict__ rgb,
              const float* __restrict__ sigma,
              float4* __restrict__ ws) {
    __shared__ float YL[YSZ2];

    const int tid   = threadIdx.x;
    const int lane  = tid & 63;
    const int wavei = tid >> 6;
    const int tx0 = blockIdx.x * TW;
    const int ty0 = blockIdx.y * BH;
    const int slice = blockIdx.z;
    const int nz = gridDim.z;

    const float* Rp = rgb;
    const float* Gp = rgb + NPX;
    const float* Bp = rgb + 2*NPX;

    // stage luminance: rows -7..14, cols -7..66 (circular)
    for (int idx = tid; idx < YSZ2; idx += 256) {
        int a = idx / YCOLS, b = idx - a*YCOLS;
        int gy = (ty0 + a - 7) & (IH-1);
        int gx = (tx0 + b - 7) & (IW-1);
        int g = gy*IW + gx;
        YL[idx] = 0.299f*Rp[g] + 0.587f*Gp[g] + 0.114f*Bp[g];
    }
    __syncthreads();

    const float m2 = -1.4426950408889634f /
                     (fmaxf(sigma[0]*2.0f, 0.0f) + 1e-6f);

    const int l  = lane;         // D col cd = l-2; output col = l (<60)
    const int r0 = wavei*2;      // strip start row (0,2,4,6)

    // minuend Y at D col cd=l-2: image rows r0-2..r0+3 (storage r0+5+i)
    float yb6[6];
    #pragma unroll
    for (int i = 0; i < 6; ++i)
        yb6[i] = YL[(r0+5+i)*YCOLS + (l+5)];

    float accR[2]={0,0}, accG[2]={0,0}, accB[2]={0,0}, den[2]={0,0};

    int dxlo, dxcnt;
    if (nz == 6) { if (slice < 5) { dxlo = -5 + 2*slice; dxcnt = 2; }
                   else           { dxlo = 5;            dxcnt = 1; } }
    else         { if (slice < 3) { dxlo = -5 + 3*slice; dxcnt = 3; }
                   else           { dxlo = 4;            dxcnt = 2; } }

    for (int u = 0; u < dxcnt; ++u) {
        const int dx = dxlo + u;
        const int ysb  = r0*YCOLS + (l + 5 - dx);     // Y subtrahend col base
        const int coli = (tx0 + l - dx) & (IW-1);     // rgb column (circular)

        // rolling Y subtrahend ring (6 slots): slot j = storage row r0+j at k=0
        float sub6[6];
        #pragma unroll
        for (int j = 0; j < 6; ++j)
            sub6[j] = YL[ysb + j*YCOLS];
        float nY = YL[ysb + 6*YCOLS];                 // storage row r0+6

        // RGB window (2 rows) + 1-deep prefetch; rows image r0-5, r0-4
        float rw[2], gw[2], bw[2];
        #pragma unroll
        for (int s = 0; s < 2; ++s) {
            int o = (((ty0 + r0 - 5 + s) & (IH-1)) << 9) + coli;
            rw[s] = Rp[o]; gw[s] = Gp[o]; bw[s] = Bp[o];
        }
        int oP = (((ty0 + r0 - 3) & (IH-1)) << 9) + coli;
        float rA = Rp[oP], gA = Gp[oP], bA = Bp[oP];  // image row r0-3
        oP = (oP + IW) & (NPX-1);                     // -> row r0-2

        #pragma unroll
        for (int k = 0; k <= 10; ++k) {               // dy = 5 - k
            if (k > 0) {
                sub6[(k+5)%6] = nY;                   // storage row r0+k+5
                if (k < 10) nY = YL[ysb + (6+k)*YCOLS];
                rw[(k+1)&1] = rA; gw[(k+1)&1] = gA; bw[(k+1)&1] = bA;
                if (k <= 9) {                         // load image row r0+k-3
                    rA = Rp[oP]; gA = Gp[oP]; bA = Bp[oP];
                    oP = (oP + IW) & (NPX-1);
                }
            }
            // own-column E + vertical box via prefix (square folded into fma)
            float pre[7]; pre[0] = 0.f;
            #pragma unroll
            for (int i = 0; i < 6; ++i) {
                float d = yb6[i] - sub6[(i+k)%6];
                pre[i+1] = fmaf(d, d, pre[i]);
            }
            float V[2];
            V[0] = pre[5] - pre[0];
            V[1] = pre[6] - pre[1];

            // horizontal 5-col box over lanes l..l+4 via chained dpp shifts
            float box[2];
            #pragma unroll
            for (int rr = 0; rr < 2; ++rr) {
                float s1 = dpp_shl1(V[rr]);           // V[l+1]
                float s2 = dpp_shl1(s1);              // V[l+2]
                float s3 = dpp_shl1(s2);              // V[l+3]
                float s4 = dpp_shl1(s3);              // V[l+4]
                box[rr] = ((V[rr] + s1) + (s2 + s3)) + s4;
            }
            #pragma unroll
            for (int rr = 0; rr < 2; ++rr) {
                float w = FEXP2(FSQRT(fmaxf(box[rr], 0.f)) * m2);
                accR[rr] = fmaf(w, rw[(k+rr)&1], accR[rr]);
                accG[rr] = fmaf(w, gw[(k+rr)&1], accG[rr]);
                accB[rr] = fmaf(w, bw[(k+rr)&1], accB[rr]);
                den[rr] += w;
            }
        }
    }

    if (l < TW && tx0 + l < IW) {
        #pragma unroll
        for (int rr = 0; rr < 2; ++rr) {
            int px = (ty0 + r0 + rr)*IW + tx0 + l;
            ws[(size_t)slice*NPX + px] =
                make_float4(accR[rr], accG[rr], accB[rr], den[rr]);
        }
    }
}

// ---------------- combine: sum nslice slices, normalize, clip ----------------
__global__ __launch_bounds__(256)
void nlm_combine(const float4* __restrict__ ws, float* __restrict__ out,
                 int nslice) {
    int px = blockIdx.x * 256 + threadIdx.x;
    float r = 0.f, g = 0.f, b = 0.f, w = 0.f;
    for (int s = 0; s < nslice; ++s) {
        float4 v = ws[(size_t)s * NPX + px];
        r += v.x; g += v.y; b += v.z; w += v.w;
    }
    float iw = 1.0f / w;
    out[px]           = fminf(fmaxf(r * iw, 0.f), 1.f);
    out[NPX + px]     = fminf(fmaxf(g * iw, 0.f), 1.f);
    out[2 * NPX + px] = fminf(fmaxf(b * iw, 0.f), 1.f);
}

// ---------------- fallback: round-5 monolithic kernel (ws too small) ---------
__global__ __launch_bounds__(256)
void nlm_mono(const float* __restrict__ rgb,
              const float* __restrict__ sigma,
              float* __restrict__ out) {
    __shared__ float Y[MYSZ];
    __shared__ float RGBL[3 * RSZ];

    const int tid = threadIdx.x;
    const int tx0 = blockIdx.x * TS;
    const int ty0 = blockIdx.y * TS;

    const float* Rp = rgb;
    const float* Gp = rgb + NPX;
    const float* Bp = rgb + 2 * NPX;

    for (int idx = tid; idx < MYSZ; idx += 256) {
        int a = idx / YD, b = idx - a * YD;
        int gy = (ty0 + a - YHALO) & (IH - 1);
        int gx = (tx0 + b - YHALO) & (IW - 1);
        int g = gy * IW + gx;
        Y[idx] = 0.299f * Rp[g] + 0.587f * Gp[g] + 0.114f * Bp[g];
    }
    for (int idx = tid; idx < RSZ; idx += 256) {
        int a = idx / RD, b = idx - a * RD;
        int gy = (ty0 + a - RHALO) & (IH - 1);
        int gx = (tx0 + b - RHALO) & (IW - 1);
        int g = gy * IW + gx;
        RGBL[idx]           = Rp[g];
        RGBL[RSZ + idx]     = Gp[g];
        RGBL[2 * RSZ + idx] = Bp[g];
    }
    __syncthreads();

    const float minv_h = -1.0f / (fmaxf(sigma[0] * 2.0f, 0.0f) + 1e-6f);
    const int tx = tid & 31;
    const int tz = tid >> 5;
    const int r0 = tz * 4;

    const int ybase = (YHALO + r0 - 2) * YD + (YHALO + tx - 2);
    float yb[8][5];
    #pragma unroll
    for (int i = 0; i < 8; ++i)
        #pragma unroll
        for (int b = 0; b < 5; ++b)
            yb[i][b] = Y[ybase + i * YD + b];

    float accR[4] = {0.f,0.f,0.f,0.f}, accG[4] = {0.f,0.f,0.f,0.f};
    float accB[4] = {0.f,0.f,0.f,0.f}, den[4] = {0.f,0.f,0.f,0.f};

    for (int dx = -5; dx <= 5; ++dx) {
        const int ybd = (YHALO + r0 - 7) * YD + (YHALO + tx - 2 - dx);
        const int rbd = (RHALO + r0 - 5) * RD + (RHALO + tx - dx);

        #pragma unroll
        for (int k = 0; k <= 10; ++k) {
            float hs[8];
            #pragma unroll
            for (int i = 0; i < 8; ++i) {
                float s = 0.f;
                #pragma unroll
                for (int b = 0; b < 5; ++b) {
                    float d = yb[i][b] - Y[ybd + (i + k) * YD + b];
                    s = fmaf(d, d, s);
                }
                hs[i] = s;
            }
            float pre[9];
            pre[0] = 0.f;
            #pragma unroll
            for (int i = 0; i < 8; ++i) pre[i + 1] = pre[i] + hs[i];
            #pragma unroll
            for (int rr = 0; rr < 4; ++rr) {
                float box = pre[rr + 5] - pre[rr];
                float w = __expf(FSQRT(box) * minv_h);
                const int s2 = rbd + (rr + k) * RD;
                accR[rr] = fmaf(w, RGBL[s2], accR[rr]);
                accG[rr] = fmaf(w, RGBL[RSZ + s2], accG[rr]);
                accB[rr] = fmaf(w, RGBL[2 * RSZ + s2], accB[rr]);
                den[rr] += w;
            }
        }
    }

    #pragma unroll
    for (int rr = 0; rr < 4; ++rr) {
        int px = (ty0 + r0 + rr) * IW + tx0 + tx;
        float iw = 1.0f / den[rr];
        out[px]           = fminf(fmaxf(accR[rr] * iw, 0.f), 1.f);
        out[NPX + px]     = fminf(fmaxf(accG[rr] * iw, 0.f), 1.f);
        out[2 * NPX + px] = fminf(fmaxf(accB[rr] * iw, 0.f), 1.f);
    }
}

extern "C" void kernel_launch(void* const* d_in, const int* in_sizes, int n_in,
                              void* d_out, int out_size, void* d_ws, size_t ws_size,
                              hipStream_t stream) {
    const float* rgb   = (const float*)d_in[0];
    const float* sigma = (const float*)d_in[1];
    float* out = (float*)d_out;

    const size_t need4 = (size_t)4 * NPX * sizeof(float4);
    if (ws_size >= need4) {
        float4* ws = (float4*)d_ws;
        dim3 grid(NXT, IH / BH, 4);        // 9 x 64 x 4 = 2304 blocks
        nlm_part<<<grid, dim3(256), 0, stream>>>(rgb, sigma, ws);
        nlm_combine<<<dim3(NPX / 256), dim3(256), 0, stream>>>(ws, out, 4);
    } else {
        dim3 grid(IW / TS, IH / TS);
        nlm_mono<<<grid, dim3(256), 0, stream>>>(rgb, sigma, out);
    }
}